// Round 1
// baseline (353.886 us; speedup 1.0000x reference)
//
#include <hip/hip_runtime.h>
#include <hip/hip_bf16.h>

// RBF kernel: out[i][j] = exp(-gamma * max(0, x2[i] + y2[j] - 2*dot(X[i], Y[j])))
// N = M = 8192, D = 512. Strategy: bf16 MFMA GEMM for the dot products
// (f32 MFMA does not exist on CDNA4), exact f32 row norms, fused epilogue.

#define N_ROWS 8192
#define D_DIM  512
#define BM 128
#define BN 128
#define BK 32

using bf16x8 = __attribute__((ext_vector_type(8))) short;  // 8 bf16 (4 VGPRs)
using f32x4  = __attribute__((ext_vector_type(4))) float;  // MFMA accumulator

__device__ inline unsigned pack2_bf16(float a, float b) {
    // round-to-nearest-even f32 -> bf16, packed pair
    unsigned ua = __builtin_bit_cast(unsigned, a);
    unsigned ub = __builtin_bit_cast(unsigned, b);
    ua = (ua + 0x7fffu + ((ua >> 16) & 1u)) >> 16;
    ub = (ub + 0x7fffu + ((ub >> 16) & 1u)) >> 16;
    return ua | (ub << 16);
}

// One wave per row: convert 512 f32 -> bf16, compute exact f32 sum of squares.
__global__ __launch_bounds__(64) void prep_kernel(const float* __restrict__ src,
                                                  unsigned short* __restrict__ dst,
                                                  float* __restrict__ norms) {
    const int row  = blockIdx.x;
    const int lane = threadIdx.x;  // 0..63
    const float4* s = reinterpret_cast<const float4*>(src) + (size_t)row * (D_DIM / 4);
    float4 v0 = s[lane * 2];
    float4 v1 = s[lane * 2 + 1];
    float ss = v0.x * v0.x + v0.y * v0.y + v0.z * v0.z + v0.w * v0.w +
               v1.x * v1.x + v1.y * v1.y + v1.z * v1.z + v1.w * v1.w;
    uint4 p;
    p.x = pack2_bf16(v0.x, v0.y);
    p.y = pack2_bf16(v0.z, v0.w);
    p.z = pack2_bf16(v1.x, v1.y);
    p.w = pack2_bf16(v1.z, v1.w);
    reinterpret_cast<uint4*>(dst + (size_t)row * D_DIM)[lane] = p;
    #pragma unroll
    for (int off = 32; off; off >>= 1) ss += __shfl_down(ss, off);
    if (lane == 0) norms[row] = ss;
}

__device__ inline void gload_lds16(const unsigned short* g, unsigned short* l) {
    __builtin_amdgcn_global_load_lds(
        (const __attribute__((address_space(1))) void*)g,
        (__attribute__((address_space(3))) void*)l, 16, 0, 0);
}

// m97-structure GEMM: 128x128 tile, BK=32, 4 waves, global_load_lds width-16,
// mfma_f32_16x16x32_bf16, fused RBF epilogue.
__global__ __launch_bounds__(256, 2) void rbf_gemm(
    const unsigned short* __restrict__ Xb, const unsigned short* __restrict__ Yb,
    const float* __restrict__ x2, const float* __restrict__ y2,
    const float* __restrict__ gptr, float* __restrict__ out) {
    __shared__ unsigned short sA[BM * BK];  // 8 KB
    __shared__ unsigned short sB[BN * BK];  // 8 KB

    // XCD-aware swizzle: 4096 blocks, 8 XCDs, 512 consecutive tiles per XCD.
    const int bid  = blockIdx.x;
    const int swz  = (bid & 7) * 512 + (bid >> 3);
    const int brow = swz >> 6;
    const int bcol = swz & 63;

    const int tid  = threadIdx.x;
    const int lane = tid & 63;
    const int wid  = tid >> 6;   // wave 0..3
    const int wr   = wid >> 1;   // wave row quadrant (0..1)
    const int wc   = wid & 1;    // wave col quadrant (0..1)

    f32x4 acc[4][4] = {};

    // Staging: each wave stages 32 rows of A and B per K-step via 2+2
    // global_load_lds (64 lanes x 16 B = 16 rows x 64 B per instruction).
    // lane covers row = chunk + lane/4, col-bytes = (lane%4)*16.
    const unsigned short* gA =
        Xb + (size_t)(brow * BM + wid * 32 + (lane >> 2)) * D_DIM + (lane & 3) * 8;
    const unsigned short* gB =
        Yb + (size_t)(bcol * BN + wid * 32 + (lane >> 2)) * D_DIM + (lane & 3) * 8;
    unsigned short* lA = sA + (wid * 32) * BK;
    unsigned short* lB = sB + (wid * 32) * BK;

    // Fragment read base: row = quadrant + m*16 + (lane&15), k = (lane>>4)*8
    const bf16x8* ra = reinterpret_cast<const bf16x8*>(
        sA + (wr * 64 + (lane & 15)) * BK + (lane >> 4) * 8);
    const bf16x8* rb = reinterpret_cast<const bf16x8*>(
        sB + (wc * 64 + (lane & 15)) * BK + (lane >> 4) * 8);

    for (int kt = 0; kt < D_DIM / BK; ++kt) {
        const unsigned short* ga = gA + kt * BK;
        const unsigned short* gb = gB + kt * BK;
        #pragma unroll
        for (int j = 0; j < 2; ++j) {
            gload_lds16(ga + j * 16 * D_DIM, lA + j * 16 * BK);
            gload_lds16(gb + j * 16 * D_DIM, lB + j * 16 * BK);
        }
        __syncthreads();  // compiler emits vmcnt(0) drain before barrier

        bf16x8 a[4], b[4];
        #pragma unroll
        for (int m = 0; m < 4; ++m) a[m] = ra[m * 64];  // m*16 rows * 32 elem / 8
        #pragma unroll
        for (int n = 0; n < 4; ++n) b[n] = rb[n * 64];
        #pragma unroll
        for (int m = 0; m < 4; ++m)
            #pragma unroll
            for (int n = 0; n < 4; ++n)
                acc[m][n] = __builtin_amdgcn_mfma_f32_16x16x32_bf16(a[m], b[n], acc[m][n], 0, 0, 0);
        __syncthreads();
    }

    // Epilogue. C/D layout: col = lane&15, row = (lane>>4)*4 + reg  [m89]
    const float g = *gptr;
    const int rbase = brow * BM + wr * 64 + ((lane >> 4) << 2);
    const int cbase = bcol * BN + wc * 64 + (lane & 15);

    float yv[4];
    #pragma unroll
    for (int n = 0; n < 4; ++n) yv[n] = y2[cbase + n * 16];
    float xv[4][4];
    #pragma unroll
    for (int m = 0; m < 4; ++m)
        #pragma unroll
        for (int r = 0; r < 4; ++r) xv[m][r] = x2[rbase + m * 16 + r];

    #pragma unroll
    for (int m = 0; m < 4; ++m) {
        #pragma unroll
        for (int r = 0; r < 4; ++r) {
            const size_t rowoff = (size_t)(rbase + m * 16 + r) * N_ROWS;
            #pragma unroll
            for (int n = 0; n < 4; ++n) {
                float sq = xv[m][r] + yv[n] - 2.0f * acc[m][n][r];
                sq = fmaxf(sq, 0.0f);
                out[rowoff + cbase + n * 16] = __expf(-g * sq);
            }
        }
    }
}

extern "C" void kernel_launch(void* const* d_in, const int* in_sizes, int n_in,
                              void* d_out, int out_size, void* d_ws, size_t ws_size,
                              hipStream_t stream) {
    const float* X = (const float*)d_in[0];
    const float* Y = (const float*)d_in[1];
    const float* gamma = (const float*)d_in[2];
    float* out = (float*)d_out;

    unsigned short* Xb = (unsigned short*)d_ws;                  // 8192*512 bf16 = 8 MB
    unsigned short* Yb = Xb + (size_t)N_ROWS * D_DIM;            // 8 MB
    float* x2 = (float*)(Yb + (size_t)N_ROWS * D_DIM);           // 32 KB
    float* y2 = x2 + N_ROWS;                                     // 32 KB

    prep_kernel<<<N_ROWS, 64, 0, stream>>>(X, Xb, x2);
    prep_kernel<<<N_ROWS, 64, 0, stream>>>(Y, Yb, y2);

    const int grid = (N_ROWS / BM) * (N_ROWS / BN);  // 4096
    rbf_gemm<<<grid, 256, 0, stream>>>(Xb, Yb, x2, y2, gamma, out);
}